// Round 1
// 1197.094 us; speedup vs baseline: 1.0935x; 1.0935x over previous
//
#include <hip/hip_runtime.h>
#include <hip/hip_fp16.h>

typedef _Float16 half8 __attribute__((ext_vector_type(8)));
typedef float floatx4 __attribute__((ext_vector_type(4)));

// workspace layout
#define HBUF_BYTES (2ull * 16 * 1024 * 8)   // [parity][group][dim] ulong (4 f16 batches) = 256 KB
#define CTL_BYTES  (32ull * 1024)           // reserved (flags retired in R5)
#define XP_OFF     (HBUF_BYTES + CTL_BYTES)
#define XP_BYTES   (512ull * 64 * 1024 * 2) // x_proj f16 [t][b][dim] = 64 MB

#define TAG_BIT    (1ull << 14)             // bit14 of h[0]: always 0 for tanh outputs

union pack4 { unsigned long long u; _Float16 h[4]; };

__device__ inline half8 cvt8(const float4 a, const float4 b) {
    half8 r;
    r[0] = (_Float16)a.x; r[1] = (_Float16)a.y; r[2] = (_Float16)a.z; r[3] = (_Float16)a.w;
    r[4] = (_Float16)b.x; r[5] = (_Float16)b.y; r[6] = (_Float16)b.z; r[7] = (_Float16)b.w;
    return r;
}

// ---------------------------------------------------------------------------
// Phase A: x_proj[t][b][n] = sum_k emb[src[b][t]][k] * W_xh[n][k] + b_xh[n]
// (unchanged this round — not the primary bottleneck)
// ---------------------------------------------------------------------------
__global__ __launch_bounds__(256) void xproj_kernel(
    const int* __restrict__ src, const float* __restrict__ emb,
    const float* __restrict__ Wxh, const float* __restrict__ bxh,
    _Float16* __restrict__ xp)
{
    __shared__ _Float16 As[128][40];
    __shared__ _Float16 Bs[128][40];

    const int tid  = threadIdx.x;
    const int lane = tid & 63;
    const int w    = tid >> 6;
    const int m15  = lane & 15;
    const int quad = lane >> 4;
    const int bid  = blockIdx.x;
    const int bn   = bid & 7;
    const int bm   = bid >> 3;
    const int m0   = bm * 128, n0 = bn * 128;
    const int wm   = w & 1, wn = w >> 1;

    const int  srow = tid >> 1;
    const int  scol = (tid & 1) * 16;
    const long arow = (long)src[m0 + srow] * 1024;
    const float* abase = emb + arow + scol;
    const float* bbase = Wxh + (long)(n0 + srow) * 1024 + scol;

    floatx4 zero4 = {0.f, 0.f, 0.f, 0.f};
    floatx4 acc[4][4];
#pragma unroll
    for (int mt = 0; mt < 4; mt++)
#pragma unroll
        for (int nt = 0; nt < 4; nt++) acc[mt][nt] = zero4;

    for (int k0 = 0; k0 < 1024; k0 += 32) {
        __syncthreads();
        float4 a0 = *(const float4*)(abase + k0);
        float4 a1 = *(const float4*)(abase + k0 + 4);
        float4 a2 = *(const float4*)(abase + k0 + 8);
        float4 a3 = *(const float4*)(abase + k0 + 12);
        float4 b0 = *(const float4*)(bbase + k0);
        float4 b1 = *(const float4*)(bbase + k0 + 4);
        float4 b2 = *(const float4*)(bbase + k0 + 8);
        float4 b3 = *(const float4*)(bbase + k0 + 12);
        *(half8*)&As[srow][scol]     = cvt8(a0, a1);
        *(half8*)&As[srow][scol + 8] = cvt8(a2, a3);
        *(half8*)&Bs[srow][scol]     = cvt8(b0, b1);
        *(half8*)&Bs[srow][scol + 8] = cvt8(b2, b3);
        __syncthreads();

        half8 af[4], bf[4];
#pragma unroll
        for (int mt = 0; mt < 4; mt++)
            af[mt] = *(const half8*)&As[wm * 64 + mt * 16 + m15][quad * 8];
#pragma unroll
        for (int nt = 0; nt < 4; nt++)
            bf[nt] = *(const half8*)&Bs[wn * 64 + nt * 16 + m15][quad * 8];
#pragma unroll
        for (int mt = 0; mt < 4; mt++)
#pragma unroll
            for (int nt = 0; nt < 4; nt++)
                acc[mt][nt] = __builtin_amdgcn_mfma_f32_16x16x32_f16(
                    af[mt], bf[nt], acc[mt][nt], 0, 0, 0);
    }

#pragma unroll
    for (int nt = 0; nt < 4; nt++) {
        const int n = n0 + wn * 64 + nt * 16 + m15;
        const float bias = bxh[n];
#pragma unroll
        for (int mt = 0; mt < 4; mt++) {
            const int mrow = m0 + wm * 64 + mt * 16 + quad * 4;
#pragma unroll
            for (int r = 0; r < 4; r++) {
                const int m = mrow + r;
                const int b = m >> 9;
                const int t = m & 511;
                xp[((long)t * 64 + b) * 1024 + n] = (_Float16)(acc[mt][nt][r] + bias);
            }
        }
    }
}

// ---------------------------------------------------------------------------
// Phase B: persistent recurrence, 256 WGs (1/CU via launch_bounds(256,1)).
// R5 SYNC: flags retired. Validity tag embedded in the h data itself:
// tanh outputs satisfy |v|<=1 so bit14 of every f16 lane is 0. We steal
// bit14 of each packed 8B word as a 1-bit epoch tag. With 2 parity buffers
// (slot reused every 2 steps), TAG(t) = ((t+1)>>1)&1 alternates per reuse,
// and the all-zero memset init reads as valid-for-t=0 / stale-for-t=1.
// Consumers poll the data words directly (same relaxed 8B agent atomics the
// old flag spin used): one memory round-trip per step instead of three
// (store-drain -> flag -> poll -> gather). 2 barriers/step instead of 4.
// Back-pressure: a producer stores h_{t+1} (overwriting h_{t-1} slots) only
// after its gather of h_t completed, which implies every member of the
// group already consumed h_{t-1}. Per-word 8B atomicity handles partial
// arrival with no fences.
// ---------------------------------------------------------------------------
__global__ __launch_bounds__(256, 1) void rnn_kernel(
    const float* __restrict__ Whh, const _Float16* __restrict__ xp,
    unsigned long long* __restrict__ hb, float* __restrict__ out)
{
    __shared__ _Float16 hstage[16][1032];       // rows 4..15 stay zero (M-pad)
    __shared__ floatx4  cred[4][4][64];         // [k-slice wave][ntile][lane]

    const int tid    = threadIdx.x;
    const int lane   = tid & 63;
    const int w      = tid >> 6;
    const int m15    = lane & 15;
    const int quad   = lane >> 4;
    const int wg     = blockIdx.x;
    const int g      = wg & 15;
    const int member = wg >> 4;
    const int b0     = g * 4;

    for (int i = tid; i < 16 * 1032; i += 256) ((_Float16*)hstage)[i] = (_Float16)0.f;

    // W_hh slice -> 128 VGPRs (f16), reused for all 512 steps
    half8 Wf[4][8];
#pragma unroll
    for (int nt = 0; nt < 4; nt++) {
        const float* wrow = Whh + (long)(member * 64 + nt * 16 + m15) * 1024
                                + w * 256 + quad * 8;
#pragma unroll
        for (int kk = 0; kk < 8; kk++) {
            float4 lo = *(const float4*)(wrow + kk * 32);
            float4 hi = *(const float4*)(wrow + kk * 32 + 4);
            Wf[nt][kk] = cvt8(lo, hi);
        }
    }
    __syncthreads();

    const int dim = member * 64 + w * 16 + m15;
    float xv[4] = {0.f, 0.f, 0.f, 0.f};
    if (quad == 0) {
#pragma unroll
        for (int r = 0; r < 4; r++)
            xv[r] = (float)xp[((long)0 * 64 + b0 + r) * 1024 + dim];
    }

    floatx4 zero4 = {0.f, 0.f, 0.f, 0.f};

    for (int t = 0; t < 512; t++) {
        const unsigned long long* hcu = hb + (size_t)(t & 1) * 16384 + (size_t)g * 1024;
        unsigned long long*       hnu = hb + (size_t)((t + 1) & 1) * 16384 + (size_t)g * 1024;
        const unsigned long long exp_tag = (unsigned long long)(((t + 1) >> 1) & 1) << 14;

        // gather h_t: poll the data words themselves until the epoch tag
        // matches, then strip the tag and transpose into LDS.
        unsigned long long v[4];
        for (;;) {
            bool ok = true;
#pragma unroll
            for (int i = 0; i < 4; i++)
                v[i] = __hip_atomic_load(hcu + tid + 256 * i, __ATOMIC_RELAXED,
                                         __HIP_MEMORY_SCOPE_AGENT);
#pragma unroll
            for (int i = 0; i < 4; i++)
                ok &= ((v[i] & TAG_BIT) == exp_tag);
            if (ok) break;
        }
#pragma unroll
        for (int i = 0; i < 4; i++) {
            pack4 p; p.u = v[i] & ~TAG_BIT;
            const int d = tid + 256 * i;
#pragma unroll
            for (int b = 0; b < 4; b++) hstage[b][d] = p.h[b];
        }
        __syncthreads();

        // partial GEMM over this wave's K-slice, 4 n-tiles
        floatx4 pacc[4];
#pragma unroll
        for (int nt = 0; nt < 4; nt++) pacc[nt] = zero4;
#pragma unroll
        for (int kk = 0; kk < 8; kk++) {
            half8 a = *(const half8*)&hstage[m15][w * 256 + kk * 32 + quad * 8];
#pragma unroll
            for (int nt = 0; nt < 4; nt++)
                pacc[nt] = __builtin_amdgcn_mfma_f32_16x16x32_f16(
                    a, Wf[nt][kk], pacc[nt], 0, 0, 0);
        }

        // cross-wave K reduction via LDS; wave w finalizes n-tile w
#pragma unroll
        for (int nt = 0; nt < 4; nt++) cred[w][nt][lane] = pacc[nt];
        __syncthreads();
        floatx4 dsum = cred[0][w][lane];
#pragma unroll
        for (int ww = 1; ww < 4; ww++) dsum += cred[ww][w][lane];

        // epilogue: quad 0 holds batches 0..3; pack + tag + one 8B atomic
        // store. The store IS the publication — consumers' polls see it.
        if (quad == 0) {
            pack4 p;
#pragma unroll
            for (int r = 0; r < 4; r++) {
                float pre  = dsum[r] + xv[r];
                float e    = __expf(2.0f * pre);
                float hval = 1.0f - 2.0f / (e + 1.0f);   // tanh
                p.h[r] = (_Float16)hval;
                if (t == 511) out[(b0 + r) * 1024 + dim] = hval;
            }
            if (t < 511) {
                const unsigned long long st_tag =
                    (unsigned long long)(((t + 2) >> 1) & 1) << 14;
                __hip_atomic_store(hnu + dim, p.u | st_tag, __ATOMIC_RELAXED,
                                   __HIP_MEMORY_SCOPE_AGENT);
            }
        }

        // prefetch x_proj for t+1; drains while next poll spins
        if (t < 511 && quad == 0) {
#pragma unroll
            for (int r = 0; r < 4; r++)
                xv[r] = (float)xp[((long)(t + 1) * 64 + b0 + r) * 1024 + dim];
        }
    }
}

extern "C" void kernel_launch(void* const* d_in, const int* in_sizes, int n_in,
                              void* d_out, int out_size, void* d_ws, size_t ws_size,
                              hipStream_t stream) {
    const int*   src = (const int*)d_in[0];
    const float* emb = (const float*)d_in[1];
    const float* Wxh = (const float*)d_in[2];
    const float* bxh = (const float*)d_in[3];
    const float* Whh = (const float*)d_in[4];
    float* out = (float*)d_out;

    char* ws = (char*)d_ws;
    unsigned long long* hb = (unsigned long long*)ws;
    _Float16* xp = (_Float16*)(ws + XP_OFF);

    // zero h[0] (f16 zeros, tag bit 0 == TAG(0)); parity-1 zeros read as
    // stale for t=1 (expects tag 1) so consumers block until real h_1.
    hipMemsetAsync(ws, 0, HBUF_BYTES, stream);

    hipLaunchKernelGGL(xproj_kernel, dim3(2048), dim3(256), 0, stream,
                       src, emb, Wxh, bxh, xp);

    hipLaunchKernelGGL(rnn_kernel, dim3(256), dim3(256), 0, stream,
                       Whh, xp, hb, out);
}